// Round 1
// 287.464 us; speedup vs baseline: 1.1102x; 1.1102x over previous
//
#include <hip/hip_runtime.h>

typedef __bf16 bf16_t;
typedef __bf16 bf16x8 __attribute__((ext_vector_type(8)));
typedef float f32x4 __attribute__((ext_vector_type(4)));
typedef unsigned short us4 __attribute__((ext_vector_type(4)));
typedef unsigned short us8 __attribute__((ext_vector_type(8)));

#define LO4(v) __builtin_shufflevector(v, v, 0, 1, 2, 3)
#define HI4(v) __builtin_shufflevector(v, v, 4, 5, 6, 7)

// ---------------- foveation ----------------
// glimpse[b, (k*3+c)*1024 + gy*32 + gx] = avgpool_F( x[b,c, st1-pad+gy*F+dy, st0-pad+gx*F+dx] )
template<int F>
__device__ __forceinline__ void fov_scale(const float* __restrict__ xb,
                                          bf16_t* __restrict__ gb,
                                          int r0, int c0, int base, int count, int kidx)
{
  constexpr float inv = 1.0f / (F * F);
  for (int i = threadIdx.x; i < count; i += 256) {
    const int idx = base + i;              // 0..3071 within this scale (c*1024 + gy*32 + gx)
    const int ch  = idx >> 10;
    const int rem = idx & 1023;
    const int gy  = rem >> 5, gx = rem & 31;
    const float* xc = xb + ch * 50176;
    float sum = 0.0f;
    const int rbase = r0 + gy * F, cbase = c0 + gx * F;
#pragma unroll
    for (int dy = 0; dy < F; ++dy) {
      const int rr = rbase + dy;
      if ((unsigned)rr < 224u) {
#pragma unroll
        for (int dx = 0; dx < F; ++dx) {
          const int cc = cbase + dx;
          if ((unsigned)cc < 224u) sum += xc[rr * 224 + cc];
        }
      }
    }
    gb[kidx * 3072 + idx] = (bf16_t)(sum * inv);
  }
}

// ---------------- 64x64 fp32 -> bf16 transpose tile (for weight pre-conversion) ----------------
// src: tile origin of [64 k][64 n] fp32, row stride srcld.
// dst: tile origin of [64 n][64 k] bf16 (as ushort), row stride dstld.
__device__ __forceinline__ void transpose_tile(const float* __restrict__ src, int srcld,
                                               unsigned short* __restrict__ dst, int dstld)
{
  __shared__ unsigned short T[64][72];   // [n][k], row stride 144B (16B aligned rows)
  const int t = threadIdx.x;
#pragma unroll
  for (int it = 0; it < 16; ++it) {
    const int idx = it * 256 + t;        // 0..4095
    const int kk = idx >> 6, nn = idx & 63;   // coalesced along nn
    T[nn][kk] = __builtin_bit_cast(unsigned short, (bf16_t)src[(size_t)kk * srcld + nn]);
  }
  __syncthreads();
#pragma unroll
  for (int it = 0; it < 2; ++it) {
    const int q = it * 256 + t;          // 0..511
    const int n = q >> 3, kc = (q & 7) * 8;
    *(us8*)(dst + (size_t)n * dstld + kc) = *(const us8*)&T[n][kc];
  }
}

// ---------------- fused foveate + weight-convert kernel ----------------
// blocks 0..1791: foveation (b = bid&255, y = bid>>8)
// blocks 1792..4095: W1 (9216x1024 fp32) -> W1t (1024n x 9216k bf16)
// blocks 4096..5119: [W3;W4] (2048x2048 fp32 logical) -> W34t (2048n x 2048k bf16)
__global__ __launch_bounds__(256) void fov_conv_kernel(const float* __restrict__ x,
                                                       const float* __restrict__ l,
                                                       bf16_t* __restrict__ g,
                                                       const float* __restrict__ W1,
                                                       const float* __restrict__ W3,
                                                       const float* __restrict__ W4,
                                                       bf16_t* __restrict__ W1t,
                                                       bf16_t* __restrict__ W34t)
{
  const int bid = blockIdx.x;
  if (bid < 1792) {
    const int b = bid & 255;
    const int y = bid >> 8;     // 7 work partitions weighted by read cost
    const float l0 = l[2 * b], l1 = l[2 * b + 1];
    // match reference exactly: (int)(0.5f * ((l + 1.0f) * 224.0f)), trunc (values >= 0)
    const int st0 = (int)(0.5f * ((l0 + 1.0f) * 224.0f));  // col start
    const int st1 = (int)(0.5f * ((l1 + 1.0f) * 224.0f));  // row start
    const float* xb = x + (size_t)b * 3 * 50176;
    bf16_t* gb = g + (size_t)b * 9216;
    if (y == 0) {
      fov_scale<1>(xb, gb, st1 - 17, st0 - 17, 0, 3072, 0);              // pad = 32/2+1
    } else if (y <= 2) {
      fov_scale<2>(xb, gb, st1 - 33, st0 - 33, (y - 1) * 1536, 1536, 1); // pad = 64/2+1
    } else {
      fov_scale<4>(xb, gb, st1 - 65, st0 - 65, (y - 3) * 768, 768, 2);   // pad = 128/2+1
    }
  } else if (bid < 4096) {
    const int cid = bid - 1792;          // 0..2303 = 144 ktiles x 16 ntiles
    const int kt = cid >> 4, nt = cid & 15;
    transpose_tile(W1 + (size_t)(kt * 64) * 1024 + nt * 64, 1024,
                   (unsigned short*)W1t + (size_t)(nt * 64) * 9216 + kt * 64, 9216);
  } else {
    const int cid = bid - 4096;          // 0..1023 = 32 ktiles x 32 ntiles
    const int kt = cid >> 5, nt = cid & 31;
    const int k0 = kt * 64;              // tile never straddles k=1024 (64 | 1024)
    const float* src = (k0 < 1024) ? (W3 + (size_t)k0 * 2048 + nt * 64)
                                   : (W4 + (size_t)(k0 - 1024) * 2048 + nt * 64);
    transpose_tile(src, 2048,
                   (unsigned short*)W34t + (size_t)(nt * 64) * 2048 + k0, 2048);
  }
}

// ---------------- split-K bf16 MFMA GEMM, both operands k-contiguous bf16 ----------------
// A: bf16 [M x KFULL] row-major. Bt: bf16 [N x KFULL] row-major (pre-transposed weights).
// Writes fp32 partials: part[z][m][n], z = blockIdx.z. M hardcoded 256.
// Reg-staged prefetch: tile k+1 loads issue right after the first barrier and land
// during the frag-read + MFMA phase (compiler places the vmcnt before next ds_write).
template<int BM, int BN, int KCHUNK, int NDIM, int KFULL>
__global__ __launch_bounds__(256) void gemm_bb(const bf16_t* __restrict__ A,
                                               const bf16_t* __restrict__ Bt,
                                               float* __restrict__ part)
{
  constexpr int WROWS = BM / 4;     // rows per wave
  constexpr int SM = WROWS / 16;    // 16-row subtiles per wave
  constexpr int SN = BN / 16;       // 16-col subtiles
  constexpr int LDA = 36;           // LDS row stride (ushorts): conflict-benign for b64 frag reads
  constexpr int NLA = BM / 64;      // us8 A loads per thread per k-step
  __shared__ unsigned short Al[BM * LDA];
  __shared__ unsigned short Bl[BN * LDA];
  const int t = threadIdx.x;
  const int w = t >> 6, lane = t & 63;
  const int lr = lane & 15, kg = lane >> 4;
  const int bm0 = blockIdx.x * BM, bn0 = blockIdx.y * BN;
  const int ks0 = blockIdx.z * KCHUNK;
  const unsigned short* Au = (const unsigned short*)A;
  const unsigned short* Bu = (const unsigned short*)Bt;

  const int bn = t >> 2, bkb = (t & 3) * 8;
  const bool bld = (t < BN * 4);    // wave-uniform (multiple-of-64 cut)

  f32x4 acc[SM][SN] = {};
  us8 pa[NLA], pb;

  // prologue: load k-tile 0 into regs
#pragma unroll
  for (int i = 0; i < NLA; ++i) {
    const int q = t + 256 * i;
    pa[i] = *(const us8*)(Au + (size_t)(bm0 + (q >> 2)) * KFULL + ks0 + (q & 3) * 8);
  }
  if (bld) pb = *(const us8*)(Bu + (size_t)(bn0 + bn) * KFULL + ks0 + bkb);

  for (int k0 = 0; k0 < KCHUNK; k0 += 32) {
    // ---- regs -> LDS ----
#pragma unroll
    for (int i = 0; i < NLA; ++i) {
      const int q = t + 256 * i;
      const int m = q >> 2, kb = (q & 3) * 8;
      *(us4*)(&Al[m * LDA + kb])     = LO4(pa[i]);
      *(us4*)(&Al[m * LDA + kb + 4]) = HI4(pa[i]);
    }
    if (bld) {
      *(us4*)(&Bl[bn * LDA + bkb])     = LO4(pb);
      *(us4*)(&Bl[bn * LDA + bkb + 4]) = HI4(pb);
    }
    __syncthreads();
    // ---- prefetch next k-tile into regs (overlaps with frag reads + MFMA) ----
    if (k0 + 32 < KCHUNK) {
      const int knext = ks0 + k0 + 32;
#pragma unroll
      for (int i = 0; i < NLA; ++i) {
        const int q = t + 256 * i;
        pa[i] = *(const us8*)(Au + (size_t)(bm0 + (q >> 2)) * KFULL + knext + (q & 3) * 8);
      }
      if (bld) pb = *(const us8*)(Bu + (size_t)(bn0 + bn) * KFULL + knext + bkb);
    }
    // ---- fragments (A[m=lr][k=kg*8+j], B[n=lr][k=kg*8+j]) + MFMA ----
    bf16x8 af[SM], bfr[SN];
#pragma unroll
    for (int sm = 0; sm < SM; ++sm) {
      const unsigned short* p = &Al[(w * WROWS + sm * 16 + lr) * LDA + kg * 8];
      us4 x0 = *(const us4*)p;
      us4 x1 = *(const us4*)(p + 4);
      af[sm] = __builtin_bit_cast(bf16x8, __builtin_shufflevector(x0, x1, 0, 1, 2, 3, 4, 5, 6, 7));
    }
#pragma unroll
    for (int sn = 0; sn < SN; ++sn) {
      const unsigned short* p = &Bl[(sn * 16 + lr) * LDA + kg * 8];
      us4 x0 = *(const us4*)p;
      us4 x1 = *(const us4*)(p + 4);
      bfr[sn] = __builtin_bit_cast(bf16x8, __builtin_shufflevector(x0, x1, 0, 1, 2, 3, 4, 5, 6, 7));
    }
#pragma unroll
    for (int sm = 0; sm < SM; ++sm)
#pragma unroll
      for (int sn = 0; sn < SN; ++sn)
        acc[sm][sn] = __builtin_amdgcn_mfma_f32_16x16x32_bf16(af[sm], bfr[sn], acc[sm][sn], 0, 0, 0);
    __syncthreads();
  }
  // ---- write fp32 partials (C/D layout: col=lr, row=kg*4+r) ----
  float* outp = part + (size_t)blockIdx.z * ((size_t)256 * NDIM);
#pragma unroll
  for (int sm = 0; sm < SM; ++sm)
#pragma unroll
    for (int sn = 0; sn < SN; ++sn)
#pragma unroll
      for (int r = 0; r < 4; ++r) {
        const int gm = bm0 + w * WROWS + sm * 16 + kg * 4 + r;
        const int gn = bn0 + sn * 16 + lr;
        outp[(size_t)gm * NDIM + gn] = acc[sm][sn][r];
      }
}

// ---------------- reduce GEMM1 partials (16) + bias + relu -> bf16; also l_out path ----------------
// A2 = [ relu(glimpse@W1+b1) | relu(l_prev@W2+b2) ]  (256 x 2048, bf16)
__global__ __launch_bounds__(256) void fuse_mid(const float* __restrict__ part1,
                                                const float* __restrict__ b1,
                                                const float* __restrict__ lprev,
                                                const float* __restrict__ W2,
                                                const float* __restrict__ b2,
                                                bf16_t* __restrict__ A2)
{
  const int idx = blockIdx.x * 256 + threadIdx.x;  // 0..524287; block-uniform branch (col chunk of 256)
  const int row = idx >> 11, col = idx & 2047;
  float s;
  if (col < 1024) {
    s = b1[col];
#pragma unroll
    for (int i = 0; i < 16; ++i) s += part1[i * 262144 + row * 1024 + col];
  } else {
    const int n = col - 1024;
    s = fmaf(lprev[2 * row], W2[n], fmaf(lprev[2 * row + 1], W2[1024 + n], b2[n]));
  }
  A2[idx] = (bf16_t)fmaxf(s, 0.0f);
}

// ---------------- reduce GEMM2 partials (8) + (b3+b4) + relu -> fp32 out ----------------
__global__ __launch_bounds__(256) void epilogue2(const float* __restrict__ part2,
                                                 const float* __restrict__ b3,
                                                 const float* __restrict__ b4,
                                                 float* __restrict__ out)
{
  const int idx = blockIdx.x * 256 + threadIdx.x;  // 0..524287
  const int col = idx & 2047;
  float s = b3[col] + b4[col];
#pragma unroll
  for (int i = 0; i < 8; ++i) s += part2[i * 524288 + idx];
  out[idx] = fmaxf(s, 0.0f);
}

extern "C" void kernel_launch(void* const* d_in, const int* in_sizes, int n_in,
                              void* d_out, int out_size, void* d_ws, size_t ws_size,
                              hipStream_t stream)
{
  const float* x     = (const float*)d_in[0];
  const float* lprev = (const float*)d_in[1];
  const float* W1    = (const float*)d_in[2];   // (9216, 1024)
  const float* b1    = (const float*)d_in[3];
  const float* W2    = (const float*)d_in[4];   // (2, 1024)
  const float* b2    = (const float*)d_in[5];
  const float* W3    = (const float*)d_in[6];   // (1024, 2048)
  const float* b3    = (const float*)d_in[7];
  const float* W4    = (const float*)d_in[8];   // (1024, 2048)
  const float* b4    = (const float*)d_in[9];
  float* out = (float*)d_out;

  // workspace layout (all 16B aligned), total ~66.6 MB (fill evidence: ws is 100s of MB)
  char* ws = (char*)d_ws;
  bf16_t* glimpse = (bf16_t*)ws;                 // 256*9216*2    =  4,718,592 B
  bf16_t* A2      = (bf16_t*)(ws + 4718592);     // 256*2048*2    =  1,048,576 B
  float*  part1   = (float*)(ws + 5767168);      // 16*256*1024*4 = 16,777,216 B
  float*  part2   = (float*)(ws + 22544384);     // 8*256*2048*4  = 16,777,216 B
  bf16_t* W1t     = (bf16_t*)(ws + 39321600);    // 1024*9216*2   = 18,874,368 B
  bf16_t* W34t    = (bf16_t*)(ws + 58195968);    // 2048*2048*2   =  8,388,608 B

  // foveation (1792 blocks) + weight transpose/convert (3328 blocks), one launch
  fov_conv_kernel<<<5120, 256, 0, stream>>>(x, lprev, glimpse, W1, W3, W4, W1t, W34t);
  // GEMM1: M=256,N=1024,K=9216; 128x64 tiles, splitK=16 (chunk 576) -> 2*16*16 = 512 blocks (2/CU)
  gemm_bb<128, 64, 576, 1024, 9216>
      <<<dim3(2, 16, 16), 256, 0, stream>>>(glimpse, W1t, part1);
  fuse_mid<<<2048, 256, 0, stream>>>(part1, b1, lprev, W2, b2, A2);
  // GEMM2: M=256,N=2048,K=2048 ([g_out|l_out]@[W3;W4]); 128x64 tiles, splitK=8 -> 2*32*8 = 512 blocks
  gemm_bb<128, 64, 256, 2048, 2048>
      <<<dim3(2, 32, 8), 256, 0, stream>>>(A2, W34t, part2);
  epilogue2<<<2048, 256, 0, stream>>>(part2, b3, b4, out);
}